// Round 1
// baseline (746.874 us; speedup 1.0000x reference)
//
#include <hip/hip_runtime.h>
#include <hip/hip_bf16.h>

// Problem constants (from reference)
#define S_LEN   2048
#define BATCH   4
#define IN_DIM  64
#define H_DIM   1024
#define DFF_DIM 1024
#define OUT_DIM 64
#define NLAYER  3
#define NHEADS  4
#define DHEAD   256     // H / NHEAD
#define WIN     4       // banded window: j in [i-4, i]
#define ROWS    (S_LEN*BATCH)  // 8192 flattened (s,b) rows, row = s*B + b
#define QKV_LD  (3*H_DIM)      // 3072

// Established facts (rounds 0-11):
//  - inputs fp32, OUTPUT fp32; seq-major rows (row = s*B+b), window stride B.
//  - r10 = 737.5 us. 128^2/BK=64 gemm_bt: QKV 60 us, MfmaUtil 35%, conflicts 0
//    => 858 TF = the m97-family structural plateau (drain-to-0 barrier).
//  - This round: QKV moves to gemm8_bt — 256^2 tile, 8-wave, 8-phase schedule
//    with COUNTED vmcnt(4) at phases 4/8 (loads stay in flight across
//    barriers) + setprio around MFMA clusters. Derived slot/deadline ledger:
//      consume: ph1-4 = buf0 (tile 2i) quadrants (0,0)(0,1)(1,0)(1,1);
//               ph5-8 = buf1 (tile 2i+1) same order.
//      stage:   ph1 buf1.A1(2i+1)  ph2 buf1.B1(2i+1)  ph3 buf0.A0(2i+2)
//               ph4 buf0.B0(2i+2)+W4  ph5 buf0.A1  ph6 buf0.B1
//               ph7 buf1.A0(2i+3)  ph8 buf1.B0(2i+3)+W8
//      every stage lands >=1 phase after its slot's last reader; W4/W8 =
//      vmcnt(4) drains exactly the half-tiles consumed in the next 4 phases.
//    Wo/W1/W2 (N=1024 -> only 128 blocks of 512thr = half the CUs) stay on
//    the 128^2 kernel; encoder (K=64) and decoder (N=64) too.

typedef __bf16 bf16x8 __attribute__((ext_vector_type(8)));
typedef float  f32x4  __attribute__((ext_vector_type(4)));

__device__ __forceinline__ float bfbits2f(unsigned int u) {
  union { unsigned int i; float f; } c; c.i = u << 16; return c.f;
}
__device__ __forceinline__ unsigned short f2bfbits(float f) {
  __hip_bfloat16 h = __float2bfloat16(f);
  return __builtin_bit_cast(unsigned short, h);
}

// async global->LDS, 16B per lane. LDS dest = wave-uniform base + lane*16.
__device__ __forceinline__ void g2l16(const void* g, void* l) {
  __builtin_amdgcn_global_load_lds((__attribute__((address_space(1))) void*)g,
                                   (__attribute__((address_space(3))) void*)l,
                                   16, 0, 0);
}

// ---------------------------------------------------------------------------
// Merged fp32->bf16 ingest: all 7 weight/src segments in ONE dispatch.
// ---------------------------------------------------------------------------
struct CvtSeg { const float* src; __hip_bfloat16* dst; int n4; };  // n4 = n/4

__global__ __launch_bounds__(256)
void cvt_all_k(CvtSeg s0, CvtSeg s1, CvtSeg s2, CvtSeg s3,
               CvtSeg s4, CvtSeg s5, CvtSeg s6)
{
  int i = blockIdx.x * 256 + threadIdx.x;   // index in unit of 4 elems
  CvtSeg seg;
  if      (i < s0.n4) { seg = s0; }
  else if ((i -= s0.n4) < s1.n4) { seg = s1; }
  else if ((i -= s1.n4) < s2.n4) { seg = s2; }
  else if ((i -= s2.n4) < s3.n4) { seg = s3; }
  else if ((i -= s3.n4) < s4.n4) { seg = s4; }
  else if ((i -= s4.n4) < s5.n4) { seg = s5; }
  else if ((i -= s5.n4) < s6.n4) { seg = s6; }
  else return;
  float4 v = *(const float4*)(seg.src + (size_t)i * 4);
  uint2 o;
  o.x = (unsigned)f2bfbits(v.x) | ((unsigned)f2bfbits(v.y) << 16);
  o.y = (unsigned)f2bfbits(v.z) | ((unsigned)f2bfbits(v.w) << 16);
  *(uint2*)(seg.dst + (size_t)i * 4) = o;
}

// ---------------------------------------------------------------------------
// gemm_bt: 128x128 tile, BK=64, 256 thr — kept for encoder/Wo/W1/W2/decoder.
// ---------------------------------------------------------------------------
template<int RELU, int OUTF32, int ADDRES>
__global__ __launch_bounds__(256, 2)
void gemm_bt(const __hip_bfloat16* __restrict__ A, int lda,
             const __hip_bfloat16* __restrict__ B,
             const float* __restrict__ bias,
             void* __restrict__ Cp, int ldc,
             const __hip_bfloat16* __restrict__ R, int ldr,
             int M, int N, int K)
{
  __shared__ __align__(16) __hip_bfloat16 As[128 * 64];
  __shared__ __align__(16) __hip_bfloat16 Bs[128 * 64];

  const int tid  = threadIdx.x;
  const int lane = tid & 63;
  const int wave = tid >> 6;
  const int quad = lane >> 4;
  const int l16  = lane & 15;

  // supertile remap: lin -> (mt, nt); 4 m-tiles per group, n fastest.
  const int gx  = gridDim.x;
  const int lin = blockIdx.y * gx + blockIdx.x;
  const int gsz = 4 * gx;
  const int mt  = (lin / gsz) * 4 + (lin & 3);
  const int nt  = (lin % gsz) >> 2;
  const int m0 = mt * 128;
  const int n0 = nt * 128;

  const int wr = (wave >> 1) * 64;   // wave's 64x64 sub-tile
  const int wc = (wave & 1) * 64;

  int arow[4], acol[4], brow[4];
#pragma unroll
  for (int s = 0; s < 4; s++) {
    const int p = tid + (s << 8);
    arow[s] = p >> 3;
    acol[s] = ((p & 7) ^ ((p >> 3) & 7)) * 8;
    brow[s] = min(n0 + arow[s], N - 1);   // clamp for N edge
  }

  f32x4 acc[4][4] = {};
  const int nk = K >> 6;

  for (int t = 0; t < nk; ++t) {
    const int k0 = t << 6;
#pragma unroll
    for (int s = 0; s < 4; s++) {
      const int lo = (wave * 64 + (s << 8)) * 8;   // chunk*8 elems
      g2l16(A + (size_t)(m0 + arow[s]) * lda + k0 + acol[s], &As[lo]);
      g2l16(B + (size_t)brow[s] * K + k0 + acol[s], &Bs[lo]);
    }
    __syncthreads();

#pragma unroll
    for (int kh = 0; kh < 2; kh++) {
      bf16x8 af[4], bfr[4];
#pragma unroll
      for (int i = 0; i < 4; i++) {
        const int row = wr + i * 16 + l16;
        const int c   = (kh * 4 + quad) ^ (row & 7);
        af[i] = *(const bf16x8*)&As[row * 64 + c * 8];
      }
#pragma unroll
      for (int j = 0; j < 4; j++) {
        const int row = wc + j * 16 + l16;
        const int c   = (kh * 4 + quad) ^ (row & 7);
        bfr[j] = *(const bf16x8*)&Bs[row * 64 + c * 8];
      }
#pragma unroll
      for (int i = 0; i < 4; i++)
#pragma unroll
        for (int j = 0; j < 4; j++)
          acc[i][j] = __builtin_amdgcn_mfma_f32_16x16x32_bf16(af[i], bfr[j], acc[i][j], 0, 0, 0);
    }
    __syncthreads();
  }

#pragma unroll
  for (int j = 0; j < 4; j++) {
    int col = n0 + wc + j * 16 + l16;
    if (col < N) {
      float bv = bias[col];
#pragma unroll
      for (int i = 0; i < 4; i++) {
        int row = m0 + wr + i * 16 + quad * 4;
#pragma unroll
        for (int r = 0; r < 4; r++) {
          float v = acc[i][j][r] + bv;
          if (RELU) v = fmaxf(v, 0.f);
          if (ADDRES) v += __bfloat162float(R[(size_t)(row + r) * ldr + col]);
          if (OUTF32) ((float*)Cp)[(size_t)(row + r) * ldc + col] = v;
          else ((__hip_bfloat16*)Cp)[(size_t)(row + r) * ldc + col] = __float2bfloat16(v);
        }
      }
    }
  }
}

// ---------------------------------------------------------------------------
// gemm8_bt: 256x256 tile, BK=64, 512 thr (8 waves, 2M x 4N), 128 KiB LDS,
// 8-phase schedule with counted vmcnt (see header ledger). Requires
// M%256==0, N%256==0, K%128==0, gridDim.y%4==0. Output bf16.
// LDS: lds[buf][slot][128*64], slot 0=A-half0, 1=A-half1, 2=B-half0, 3=B-half1.
// Swizzle identical to gemm_bt: chunk col8 = c ^ (row&7), pre-swizzled source.
// ---------------------------------------------------------------------------
#define G8_STAGE(SLOTPTR, GBASE, LD)                                          \
  do {                                                                        \
    const __hip_bfloat16* gb_ = (GBASE);                                      \
    g2l16(gb_ + (size_t)sr0 * (LD) + sc8x8, (SLOTPTR) + (wave << 9));         \
    g2l16(gb_ + (size_t)sr1 * (LD) + sc8x8, (SLOTPTR) + 4096 + (wave << 9));  \
  } while (0)

#define G8_PHASE(BUF, QM, QN, STAGE_STMT, WAIT_STMT)                          \
  do {                                                                        \
    bf16x8 af[4][2], bfr[2][2];                                               \
    const __hip_bfloat16* Asl = &lds[BUF][QM][0];                             \
    const __hip_bfloat16* Bsl = &lds[BUF][2 + (QN)][0];                       \
    _Pragma("unroll") for (int im = 0; im < 4; im++) {                        \
      const int r = wrA + im * 16;                                            \
      const int sw = r & 7;                                                   \
      _Pragma("unroll") for (int ks = 0; ks < 2; ks++)                        \
        af[im][ks] = *(const bf16x8*)&Asl[r * 64 + (((ks * 4 + quad) ^ sw) << 3)]; \
    }                                                                         \
    _Pragma("unroll") for (int jn = 0; jn < 2; jn++) {                        \
      const int r = wrB + jn * 16;                                            \
      const int sw = r & 7;                                                   \
      _Pragma("unroll") for (int ks = 0; ks < 2; ks++)                        \
        bfr[jn][ks] = *(const bf16x8*)&Bsl[r * 64 + (((ks * 4 + quad) ^ sw) << 3)]; \
    }                                                                         \
    STAGE_STMT;                                                               \
    WAIT_STMT;                                                                \
    __builtin_amdgcn_s_barrier();                                             \
    asm volatile("s_waitcnt lgkmcnt(0)" ::: "memory");                        \
    __builtin_amdgcn_sched_barrier(0);                                        \
    __builtin_amdgcn_s_setprio(1);                                            \
    _Pragma("unroll") for (int ks = 0; ks < 2; ks++)                          \
      _Pragma("unroll") for (int im = 0; im < 4; im++)                        \
        _Pragma("unroll") for (int jn = 0; jn < 2; jn++)                      \
          acc[(QM) * 4 + im][(QN) * 2 + jn] =                                 \
              __builtin_amdgcn_mfma_f32_16x16x32_bf16(                        \
                  af[im][ks], bfr[jn][ks],                                    \
                  acc[(QM) * 4 + im][(QN) * 2 + jn], 0, 0, 0);                \
    __builtin_amdgcn_s_setprio(0);                                            \
    __builtin_amdgcn_s_barrier();                                             \
  } while (0)

template<int RELU, int ADDRES>
__global__ __launch_bounds__(512, 2)
void gemm8_bt(const __hip_bfloat16* __restrict__ A, int lda,
              const __hip_bfloat16* __restrict__ B,
              const float* __restrict__ bias,
              __hip_bfloat16* __restrict__ C, int ldc,
              const __hip_bfloat16* __restrict__ Rr, int ldr,
              int N, int K)
{
  __shared__ __align__(16) __hip_bfloat16 lds[2][4][128 * 64];  // 128 KiB

  const int tid  = threadIdx.x;
  const int lane = tid & 63;
  const int wave = tid >> 6;
  const int quad = lane >> 4;
  const int l16  = lane & 15;
  const int wm   = wave >> 2;        // 0..1 (M)
  const int wn   = wave & 3;         // 0..3 (N)
  const int wrA  = wm * 64 + l16;    // slot-relative A row base
  const int wrB  = wn * 32 + l16;    // slot-relative B row base

  // staging geometry: half-tile = 128 rows x 8 chunks(16B) = 1024 chunks;
  // thread handles physical chunks p = tid + 512*s; source col8 = (p&7)^(row&7).
  const int sr0   = tid >> 3;                       // 0..63
  const int sr1   = sr0 + 64;                       // 64..127 (same low-3 bits)
  const int sc8x8 = (((tid & 7) ^ (sr0 & 7)) << 3); // source col in elems

  // supertile remap (same as gemm_bt; needs gridDim.y % 4 == 0)
  const int gx  = gridDim.x;
  const int lin = blockIdx.y * gx + blockIdx.x;
  const int gsz = 4 * gx;
  const int mt  = (lin / gsz) * 4 + (lin & 3);
  const int nt  = (lin % gsz) >> 2;
  const int m0 = mt * 256;
  const int n0 = nt * 256;

  const __hip_bfloat16* Ab = A + (size_t)m0 * lda;
  const __hip_bfloat16* Bb = B + (size_t)n0 * K;

  f32x4 acc[8][4] = {};
  const int NI = K >> 7;   // K/128: 2 K-tiles (BK=64) per iteration

  // ---- prologue: tile0 all 4 halves + tile1 A0/B0; leave 2 half-tiles in flight
  G8_STAGE(&lds[0][0][0], Ab, lda);                          // K0.A0
  G8_STAGE(&lds[0][2][0], Bb, K);                            // K0.B0
  G8_STAGE(&lds[0][1][0], Ab + (size_t)128 * lda, lda);      // K0.A1
  G8_STAGE(&lds[0][3][0], Bb + (size_t)128 * K, K);          // K0.B1
  G8_STAGE(&lds[1][0][0], Ab + 64, lda);                     // K1.A0
  G8_STAGE(&lds[1][2][0], Bb + 64, K);                       // K1.B0
  asm volatile("s_waitcnt vmcnt(4)" ::: "memory");           // K0 landed
  __builtin_amdgcn_s_barrier();

  for (int i = 0; i < NI; ++i) {
    const int k1 = (2 * i + 1) << 6;   // K-tile 2i+1 byte-col offset (elems)
    const int k2 = k1 + 64;            // K-tile 2i+2
    const int k3 = k1 + 128;           // K-tile 2i+3
    const bool pf = (i + 1 < NI);      // prefetch valid?

    G8_PHASE(0, 0, 0,
             G8_STAGE(&lds[1][1][0], Ab + (size_t)128 * lda + k1, lda), );
    G8_PHASE(0, 0, 1,
             G8_STAGE(&lds[1][3][0], Bb + (size_t)128 * K + k1, K), );
    G8_PHASE(0, 1, 0,
             if (pf) G8_STAGE(&lds[0][0][0], Ab + k2, lda), );
    G8_PHASE(0, 1, 1,
             if (pf) G8_STAGE(&lds[0][2][0], Bb + k2, K),
             if (pf) { asm volatile("s_waitcnt vmcnt(4)" ::: "memory"); }
             else    { asm volatile("s_waitcnt vmcnt(0)" ::: "memory"); });
    G8_PHASE(1, 0, 0,
             if (pf) G8_STAGE(&lds[0][1][0], Ab + (size_t)128 * lda + k2, lda), );
    G8_PHASE(1, 0, 1,
             if (pf) G8_STAGE(&lds[0][3][0], Bb + (size_t)128 * K + k2, K), );
    G8_PHASE(1, 1, 0,
             if (pf) G8_STAGE(&lds[1][0][0], Ab + k3, lda), );
    G8_PHASE(1, 1, 1,
             if (pf) G8_STAGE(&lds[1][2][0], Bb + k3, K),
             asm volatile("s_waitcnt vmcnt(4)" ::: "memory"));
  }

  // ---- epilogue: C/D layout col = lane&15, row = quad*4 + reg ----
#pragma unroll
  for (int qm = 0; qm < 2; qm++)
#pragma unroll
    for (int im = 0; im < 4; im++)
#pragma unroll
      for (int qn = 0; qn < 2; qn++)
#pragma unroll
        for (int jn = 0; jn < 2; jn++) {
          const int row0 = m0 + qm * 128 + wm * 64 + im * 16 + quad * 4;
          const int col  = n0 + qn * 128 + wn * 32 + jn * 16 + l16;
          const float bv = bias[col];
          const f32x4 a  = acc[qm * 4 + im][qn * 2 + jn];
#pragma unroll
          for (int r = 0; r < 4; r++) {
            float v = a[r] + bv;
            if (RELU) v = fmaxf(v, 0.f);
            if (ADDRES) v += __bfloat162float(Rr[(size_t)(row0 + r) * ldr + col]);
            C[(size_t)(row0 + r) * ldc + col] = __float2bfloat16(v);
          }
        }
}

// ---------------------------------------------------------------------------
// Banded attention (one wave per (s,b,h)).
// ---------------------------------------------------------------------------
__global__ __launch_bounds__(256)
void attn_k(__hip_bfloat16* __restrict__ qkv)
{
  const int gw   = (blockIdx.x << 2) + (threadIdx.x >> 6);
  const int lane = threadIdx.x & 63;
  const int h = gw & (NHEADS - 1);
  const int b = (gw >> 2) & (BATCH - 1);
  const int s = gw >> 4;
  const size_t hoff = (size_t)h * DHEAD + (lane << 2);

  float q0, q1, q2, q3;
  {
    uint2 t = *(const uint2*)(qkv + (size_t)(s * BATCH + b) * QKV_LD + hoff);
    q0 = bfbits2f(t.x & 0xffff); q1 = bfbits2f(t.x >> 16);
    q2 = bfbits2f(t.y & 0xffff); q3 = bfbits2f(t.y >> 16);
  }

  float sc[WIN + 1];
#pragma unroll
  for (int jj = 0; jj <= WIN; jj++) {
    int j = s - WIN + jj;           // wave-uniform
    float v = -1e30f;
    if (j >= 0) {
      uint2 t = *(const uint2*)(qkv + (size_t)(j * BATCH + b) * QKV_LD + H_DIM + hoff);
      float p = q0 * bfbits2f(t.x & 0xffff) + q1 * bfbits2f(t.x >> 16)
              + q2 * bfbits2f(t.y & 0xffff) + q3 * bfbits2f(t.y >> 16);
#pragma unroll
      for (int o = 32; o; o >>= 1) p += __shfl_xor(p, o);
      v = p * 0.0625f;              // 1/sqrt(256)
    }
    sc[jj] = v;
  }

  float mx = sc[0];
#pragma unroll
  for (int jj = 1; jj <= WIN; jj++) mx = fmaxf(mx, sc[jj]);
  float p[WIN + 1], den = 0.f;
#pragma unroll
  for (int jj = 0; jj <= WIN; jj++) { p[jj] = __expf(sc[jj] - mx); den += p[jj]; }

  float a0 = 0.f, a1 = 0.f, a2 = 0.f, a3 = 0.f;
#pragma unroll
  for (int jj = 0; jj <= WIN; jj++) {
    int j = s - WIN + jj;
    if (j >= 0) {
      uint2 t = *(const uint2*)(qkv + (size_t)(j * BATCH + b) * QKV_LD + 2 * H_DIM + hoff);
      a0 += p[jj] * bfbits2f(t.x & 0xffff); a1 += p[jj] * bfbits2f(t.x >> 16);
      a2 += p[jj] * bfbits2f(t.y & 0xffff); a3 += p[jj] * bfbits2f(t.y >> 16);
    }
  }
  float rl = 1.f / den;
  uint2 o;
  o.x = (unsigned)f2bfbits(a0 * rl) | ((unsigned)f2bfbits(a1 * rl) << 16);
  o.y = (unsigned)f2bfbits(a2 * rl) | ((unsigned)f2bfbits(a3 * rl) << 16);
  *(uint2*)(qkv + (size_t)(s * BATCH + b) * QKV_LD + hoff) = o;  // ctx -> q slot
}

// ---------------------------------------------------------------------------
// LayerNorm, one wave per row (shuffle-only).
// ---------------------------------------------------------------------------
__global__ __launch_bounds__(256)
void ln_k(const __hip_bfloat16* __restrict__ y, int ys,
          const float* __restrict__ g, const float* __restrict__ be,
          __hip_bfloat16* __restrict__ xout)
{
  const int row  = blockIdx.x * 4 + (threadIdx.x >> 6);
  const int lane = threadIdx.x & 63;
  const int e0   = lane * 16;
  const __hip_bfloat16* yp = y + (size_t)row * ys + e0;

  uint2 v[4];
  *(uint4*)&v[0] = *(const uint4*)yp;
  *(uint4*)&v[2] = *(const uint4*)(yp + 8);
  float t[16];
#pragma unroll
  for (int k = 0; k < 4; k++) {
    t[k * 4 + 0] = bfbits2f(v[k].x & 0xffff);
    t[k * 4 + 1] = bfbits2f(v[k].x >> 16);
    t[k * 4 + 2] = bfbits2f(v[k].y & 0xffff);
    t[k * 4 + 3] = bfbits2f(v[k].y >> 16);
  }
  float s = 0.f, ss = 0.f;
#pragma unroll
  for (int k = 0; k < 16; k++) { s += t[k]; ss += t[k] * t[k]; }
#pragma unroll
  for (int o = 32; o; o >>= 1) { s += __shfl_xor(s, o); ss += __shfl_xor(ss, o); }

  const float inv  = 1.f / (float)H_DIM;
  const float mean = s * inv;
  const float var  = ss * inv - mean * mean;   // biased var (jnp.var default)
  const float rstd = rsqrtf(var + 1e-5f);

  float4 gv[4], bv[4];
#pragma unroll
  for (int k = 0; k < 4; k++) {
    gv[k] = *(const float4*)(g + e0 + k * 4);
    bv[k] = *(const float4*)(be + e0 + k * 4);
  }
  uint2 ob[4];
#pragma unroll
  for (int k = 0; k < 4; k++) {
    float o0 = (t[k*4+0] - mean) * rstd * gv[k].x + bv[k].x;
    float o1 = (t[k*4+1] - mean) * rstd * gv[k].y + bv[k].y;
    float o2 = (t[k*4+2] - mean) * rstd * gv[k].z + bv[k].z;
    float o3 = (t[k*4+3] - mean) * rstd * gv[k].w + bv[k].w;
    ob[k].x = (unsigned)f2bfbits(o0) | ((unsigned)f2bfbits(o1) << 16);
    ob[k].y = (unsigned)f2bfbits(o2) | ((unsigned)f2bfbits(o3) << 16);
  }
  __hip_bfloat16* xp = xout + (size_t)row * H_DIM + e0;
  *(uint4*)xp       = *(const uint4*)&ob[0];
  *(uint4*)(xp + 8) = *(const uint4*)&ob[2];
}

// ---------------------------------------------------------------------------
extern "C" void kernel_launch(void* const* d_in, const int* in_sizes, int n_in,
                              void* d_out, int out_size, void* d_ws, size_t ws_size,
                              hipStream_t stream) {
  const float* src   = (const float*)d_in[0];
  const float* Wenc  = (const float*)d_in[1];
  const float* benc  = (const float*)d_in[2];
  const float* Wqkv  = (const float*)d_in[3];
  const float* bqkv  = (const float*)d_in[4];
  const float* Wo    = (const float*)d_in[5];
  const float* bo    = (const float*)d_in[6];
  const float* W1    = (const float*)d_in[7];
  const float* b1    = (const float*)d_in[8];
  const float* W2    = (const float*)d_in[9];
  const float* b2    = (const float*)d_in[10];
  const float* ln1s  = (const float*)d_in[11];
  const float* ln1b  = (const float*)d_in[12];
  const float* ln2s  = (const float*)d_in[13];
  const float* ln2b  = (const float*)d_in[14];
  const float* Wout  = (const float*)d_in[15];
  const float* bout  = (const float*)d_in[16];

  // ---- workspace (104 MiB total — footprint validated rounds 3/6) ----
  char* ws = (char*)d_ws;
  __hip_bfloat16* WB   = (__hip_bfloat16*)ws;      // bf16 arena (~37.3 MiB)
  __hip_bfloat16* srcb = WB;                       //   524288
  __hip_bfloat16* wenc = WB + 524288;              //    65536
  __hip_bfloat16* wqkv = WB + 589824;              //  9437184
  __hip_bfloat16* wo   = WB + 10027008;            //  3145728
  __hip_bfloat16* w1   = WB + 13172736;            //  3145728
  __hip_bfloat16* w2   = WB + 16318464;            //  3145728
  __hip_bfloat16* wout = WB + 19464192;            //    65536
  __hip_bfloat16* xb  = (__hip_bfloat16*)(ws + (size_t)40 * 1048576);  // 16 MiB
  __hip_bfloat16* qkv = (__hip_bfloat16*)(ws + (size_t)56 * 1048576);  // 48 MiB
  __hip_bfloat16* ctxp = qkv;             // q slot — attn output
  __hip_bfloat16* ybuf = qkv + H_DIM;     // k slot — (x + attn_out) / (x + ff)
  __hip_bfloat16* hbuf = qkv + 2 * H_DIM; // v slot — relu hidden temp

  const dim3 blk(256);

  // ---- ingest: all fp32 weights/src -> bf16 in ONE dispatch ----
  {
    CvtSeg s0{src,  srcb, 524288 / 4};
    CvtSeg s1{Wenc, wenc, 65536 / 4};
    CvtSeg s2{Wqkv, wqkv, 9437184 / 4};
    CvtSeg s3{Wo,   wo,   3145728 / 4};
    CvtSeg s4{W1,   w1,   3145728 / 4};
    CvtSeg s5{W2,   w2,   3145728 / 4};
    CvtSeg s6{Wout, wout, 65536 / 4};
    const int tot4 = (524288 + 65536 + 9437184 + 3 * 3145728 + 65536) / 4;
    cvt_all_k<<<dim3((tot4 + 255) / 256), blk, 0, stream>>>(s0, s1, s2, s3, s4, s5, s6);
  }

  // ---- encoder: x = src @ Wenc^T + benc   [8192,1024] (K=64 -> 1 tile) ----
  gemm_bt<0, 0, 0><<<dim3(H_DIM / 128, ROWS / 128), blk, 0, stream>>>(
      srcb, IN_DIM, wenc, benc, xb, H_DIM, nullptr, 0, ROWS, H_DIM, IN_DIM);

  for (int l = 0; l < NLAYER; l++) {
    // qkv = x @ Wqkv^T + bqkv   [8192,3072] — 256^2 8-phase kernel
    gemm8_bt<0, 0><<<dim3(QKV_LD / 256, ROWS / 256), dim3(512), 0, stream>>>(
        xb, H_DIM, wqkv + (size_t)l * QKV_LD * H_DIM, bqkv + l * QKV_LD,
        qkv, QKV_LD, nullptr, 0, QKV_LD, H_DIM);
    // banded attention; ctx -> q slot
    attn_k<<<dim3(ROWS * NHEADS / 4), blk, 0, stream>>>(qkv);
    // ybuf = x + ctx @ Wo^T + bo   (residual fused in epilogue)
    gemm_bt<0, 0, 1><<<dim3(H_DIM / 128, ROWS / 128), blk, 0, stream>>>(
        ctxp, QKV_LD, wo + (size_t)l * H_DIM * H_DIM, bo + l * H_DIM,
        ybuf, QKV_LD, xb, H_DIM, ROWS, H_DIM, H_DIM);
    // x = LN(ybuf)
    ln_k<<<dim3(ROWS / 4), blk, 0, stream>>>(ybuf, QKV_LD, ln1s + l * H_DIM, ln1b + l * H_DIM, xb);
    // h = relu(x @ W1^T + b1) -> hbuf (v slot)
    gemm_bt<1, 0, 0><<<dim3(DFF_DIM / 128, ROWS / 128), blk, 0, stream>>>(
        xb, H_DIM, w1 + (size_t)l * DFF_DIM * H_DIM, b1 + l * DFF_DIM,
        hbuf, QKV_LD, nullptr, 0, ROWS, DFF_DIM, H_DIM);
    // ybuf = x + h @ W2^T + b2   (residual fused in epilogue)
    gemm_bt<0, 0, 1><<<dim3(H_DIM / 128, ROWS / 128), blk, 0, stream>>>(
        hbuf, QKV_LD, w2 + (size_t)l * H_DIM * DFF_DIM, b2 + l * H_DIM,
        ybuf, QKV_LD, xb, H_DIM, ROWS, H_DIM, DFF_DIM);
    // x = LN(ybuf)
    ln_k<<<dim3(ROWS / 4), blk, 0, stream>>>(ybuf, QKV_LD, ln2s + l * H_DIM, ln2b + l * H_DIM, xb);
  }

  // ---- decoder: out = x @ Wout^T + bout   [8192,64] FP32 OUTPUT ----
  gemm_bt<0, 1, 0><<<dim3(1, ROWS / 128), blk, 0, stream>>>(
      xb, H_DIM, wout, bout, d_out, OUT_DIM, nullptr, 0, ROWS, OUT_DIM, H_DIM);
}

// Round 2
// 697.655 us; speedup vs baseline: 1.0705x; 1.0705x over previous
//
#include <hip/hip_runtime.h>
#include <hip/hip_bf16.h>

// Problem constants (from reference)
#define S_LEN   2048
#define BATCH   4
#define IN_DIM  64
#define H_DIM   1024
#define DFF_DIM 1024
#define OUT_DIM 64
#define NLAYER  3
#define NHEADS  4
#define DHEAD   256     // H / NHEAD
#define WIN     4       // banded window: j in [i-4, i]
#define ROWS    (S_LEN*BATCH)  // 8192 flattened (s,b) rows, row = s*B + b
#define QKV_LD  (3*H_DIM)      // 3072

// Established facts (rounds 0-12):
//  - r10 = 737.5 us; 128^2 gemm_bt = 858 TF plateau (drain-to-0 barrier).
//  - r11 FAILED (78 us QKV, MfmaUtil 25%): 256^2 8-phase port re-read each
//    A/B fragment from LDS in every quadrant phase (48 ds_read/K-tile/wave,
//    2x the m201 minimum) -> LDS-read-bound; plus 384-tile grid on 256 CUs
//    (75% packing) and NI=8 fill. Lesson: fragments must be read ONCE.
//  - r12 (this): gemm3r_bt — 128x256 tile, 8 waves (2Mx4N), wave owns 64x64,
//    8 ds_read + 16 MFMA per phase, 2 phases/K-tile (= minimal 16 reads /
//    32 MFMA / K-tile). 3-buffer LDS ring (144 KB), stage tile t+2 during
//    tile t, counted vmcnt(6) (never 0 mid-loop), setprio around MFMA.
//    Grids: QKV 12x64=768 (3 exact rounds), Wo/W1/W2 4x64=256 (1 round).
//    Ledger: phA(t): read ks0(buf t%3); stage A,Bh0(t+2 -> buf (t+2)%3).
//            phB(t): read ks1; stage Bh1(t+2); vmcnt(6) [drains tile t+1's
//            6 loads, leaves t+2's 6 in flight]; tails use vmcnt(0).
//    Overwrite-safety: buf (t+2)%3 last read at phB(t-1) (tile t-1), done
//    before phA(t) issues g2l (closing barrier + lgkmcnt discipline).

typedef __bf16 bf16x8 __attribute__((ext_vector_type(8)));
typedef float  f32x4  __attribute__((ext_vector_type(4)));

__device__ __forceinline__ float bfbits2f(unsigned int u) {
  union { unsigned int i; float f; } c; c.i = u << 16; return c.f;
}
__device__ __forceinline__ unsigned short f2bfbits(float f) {
  __hip_bfloat16 h = __float2bfloat16(f);
  return __builtin_bit_cast(unsigned short, h);
}

// async global->LDS, 16B per lane. LDS dest = wave-uniform base + lane*16.
__device__ __forceinline__ void g2l16(const void* g, void* l) {
  __builtin_amdgcn_global_load_lds((__attribute__((address_space(1))) void*)g,
                                   (__attribute__((address_space(3))) void*)l,
                                   16, 0, 0);
}

// ---------------------------------------------------------------------------
// Merged fp32->bf16 ingest: all 7 weight/src segments in ONE dispatch.
// ---------------------------------------------------------------------------
struct CvtSeg { const float* src; __hip_bfloat16* dst; int n4; };  // n4 = n/4

__global__ __launch_bounds__(256)
void cvt_all_k(CvtSeg s0, CvtSeg s1, CvtSeg s2, CvtSeg s3,
               CvtSeg s4, CvtSeg s5, CvtSeg s6)
{
  int i = blockIdx.x * 256 + threadIdx.x;   // index in unit of 4 elems
  CvtSeg seg;
  if      (i < s0.n4) { seg = s0; }
  else if ((i -= s0.n4) < s1.n4) { seg = s1; }
  else if ((i -= s1.n4) < s2.n4) { seg = s2; }
  else if ((i -= s2.n4) < s3.n4) { seg = s3; }
  else if ((i -= s3.n4) < s4.n4) { seg = s4; }
  else if ((i -= s4.n4) < s5.n4) { seg = s5; }
  else if ((i -= s5.n4) < s6.n4) { seg = s6; }
  else return;
  float4 v = *(const float4*)(seg.src + (size_t)i * 4);
  uint2 o;
  o.x = (unsigned)f2bfbits(v.x) | ((unsigned)f2bfbits(v.y) << 16);
  o.y = (unsigned)f2bfbits(v.z) | ((unsigned)f2bfbits(v.w) << 16);
  *(uint2*)(seg.dst + (size_t)i * 4) = o;
}

// ---------------------------------------------------------------------------
// gemm_bt: 128x128 tile, BK=64, 256 thr — kept for encoder (K=64) and
// decoder (N=64). Handles N edge via clamp + epilogue guard.
// ---------------------------------------------------------------------------
template<int RELU, int OUTF32, int ADDRES>
__global__ __launch_bounds__(256, 2)
void gemm_bt(const __hip_bfloat16* __restrict__ A, int lda,
             const __hip_bfloat16* __restrict__ B,
             const float* __restrict__ bias,
             void* __restrict__ Cp, int ldc,
             const __hip_bfloat16* __restrict__ R, int ldr,
             int M, int N, int K)
{
  __shared__ __align__(16) __hip_bfloat16 As[128 * 64];
  __shared__ __align__(16) __hip_bfloat16 Bs[128 * 64];

  const int tid  = threadIdx.x;
  const int lane = tid & 63;
  const int wave = tid >> 6;
  const int quad = lane >> 4;
  const int l16  = lane & 15;

  // supertile remap: lin -> (mt, nt); 4 m-tiles per group, n fastest.
  const int gx  = gridDim.x;
  const int lin = blockIdx.y * gx + blockIdx.x;
  const int gsz = 4 * gx;
  const int mt  = (lin / gsz) * 4 + (lin & 3);
  const int nt  = (lin % gsz) >> 2;
  const int m0 = mt * 128;
  const int n0 = nt * 128;

  const int wr = (wave >> 1) * 64;   // wave's 64x64 sub-tile
  const int wc = (wave & 1) * 64;

  int arow[4], acol[4], brow[4];
#pragma unroll
  for (int s = 0; s < 4; s++) {
    const int p = tid + (s << 8);
    arow[s] = p >> 3;
    acol[s] = ((p & 7) ^ ((p >> 3) & 7)) * 8;
    brow[s] = min(n0 + arow[s], N - 1);   // clamp for N edge
  }

  f32x4 acc[4][4] = {};
  const int nk = K >> 6;

  for (int t = 0; t < nk; ++t) {
    const int k0 = t << 6;
#pragma unroll
    for (int s = 0; s < 4; s++) {
      const int lo = (wave * 64 + (s << 8)) * 8;   // chunk*8 elems
      g2l16(A + (size_t)(m0 + arow[s]) * lda + k0 + acol[s], &As[lo]);
      g2l16(B + (size_t)brow[s] * K + k0 + acol[s], &Bs[lo]);
    }
    __syncthreads();

#pragma unroll
    for (int kh = 0; kh < 2; kh++) {
      bf16x8 af[4], bfr[4];
#pragma unroll
      for (int i = 0; i < 4; i++) {
        const int row = wr + i * 16 + l16;
        const int c   = (kh * 4 + quad) ^ (row & 7);
        af[i] = *(const bf16x8*)&As[row * 64 + c * 8];
      }
#pragma unroll
      for (int j = 0; j < 4; j++) {
        const int row = wc + j * 16 + l16;
        const int c   = (kh * 4 + quad) ^ (row & 7);
        bfr[j] = *(const bf16x8*)&Bs[row * 64 + c * 8];
      }
#pragma unroll
      for (int i = 0; i < 4; i++)
#pragma unroll
        for (int j = 0; j < 4; j++)
          acc[i][j] = __builtin_amdgcn_mfma_f32_16x16x32_bf16(af[i], bfr[j], acc[i][j], 0, 0, 0);
    }
    __syncthreads();
  }

#pragma unroll
  for (int j = 0; j < 4; j++) {
    int col = n0 + wc + j * 16 + l16;
    if (col < N) {
      float bv = bias[col];
#pragma unroll
      for (int i = 0; i < 4; i++) {
        int row = m0 + wr + i * 16 + quad * 4;
#pragma unroll
        for (int r = 0; r < 4; r++) {
          float v = acc[i][j][r] + bv;
          if (RELU) v = fmaxf(v, 0.f);
          if (ADDRES) v += __bfloat162float(R[(size_t)(row + r) * ldr + col]);
          if (OUTF32) ((float*)Cp)[(size_t)(row + r) * ldc + col] = v;
          else ((__hip_bfloat16*)Cp)[(size_t)(row + r) * ldc + col] = __float2bfloat16(v);
        }
      }
    }
  }
}

// ---------------------------------------------------------------------------
// gemm3r_bt: 128(M)x256(N) tile, BK=64, 512 thr (8 waves 2Mx4N, wave owns
// 64x64), 3-buffer LDS ring (48 KB/buf: A 128x64 @0, B 256x64 @8192 elems),
// counted vmcnt(6), setprio MFMA clusters. Requires M%128==0, N%256==0,
// K%64==0, K>=128, gridDim.y%4==0. Output bf16.
// Swizzle: chunk col8 = c ^ (row&7), pre-swizzled global source (conflict-
// free both sides — measured 0 in r0/r1 with identical pattern).
// ---------------------------------------------------------------------------
#define R3_SA(BUF, KO)                                                        \
  do {                                                                        \
    __hip_bfloat16* d_ = &lds[BUF][0];                                        \
    _Pragma("unroll") for (int s_ = 0; s_ < 2; s_++)                          \
      g2l16(Ab + (size_t)arow[s_] * lda + (KO) + acol[s_],                    \
            d_ + (((wave << 6) + (s_ << 9)) << 3));                           \
  } while (0)
#define R3_SB0(BUF, KO)                                                       \
  do {                                                                        \
    __hip_bfloat16* d_ = &lds[BUF][8192];                                     \
    _Pragma("unroll") for (int s_ = 0; s_ < 2; s_++)                          \
      g2l16(Bb + (size_t)arow[s_] * K + (KO) + acol[s_],                      \
            d_ + (((wave << 6) + (s_ << 9)) << 3));                           \
  } while (0)
#define R3_SB1(BUF, KO)                                                       \
  do {                                                                        \
    __hip_bfloat16* d_ = &lds[BUF][8192];                                     \
    _Pragma("unroll") for (int s_ = 2; s_ < 4; s_++)                          \
      g2l16(Bb + (size_t)arow[s_] * K + (KO) + acol[s_],                      \
            d_ + (((wave << 6) + (s_ << 9)) << 3));                           \
  } while (0)

#define R3_PH(BUF, KS, STAGE_STMT, WAIT_STMT)                                 \
  do {                                                                        \
    bf16x8 af[4], bq[4];                                                      \
    const __hip_bfloat16* As_ = &lds[BUF][0];                                 \
    const __hip_bfloat16* Bs_ = &lds[BUF][8192];                              \
    _Pragma("unroll") for (int im = 0; im < 4; im++) {                        \
      const int r_ = wm * 64 + im * 16 + l16;                                 \
      af[im] = *(const bf16x8*)&As_[r_ * 64 + ((((KS)*4 + quad) ^ (r_ & 7)) << 3)]; \
    }                                                                         \
    _Pragma("unroll") for (int jn = 0; jn < 4; jn++) {                        \
      const int r_ = wn * 64 + jn * 16 + l16;                                 \
      bq[jn] = *(const bf16x8*)&Bs_[r_ * 64 + ((((KS)*4 + quad) ^ (r_ & 7)) << 3)]; \
    }                                                                         \
    STAGE_STMT;                                                               \
    WAIT_STMT;                                                                \
    __builtin_amdgcn_s_barrier();                                             \
    asm volatile("s_waitcnt lgkmcnt(0)" ::: "memory");                        \
    __builtin_amdgcn_sched_barrier(0);                                        \
    __builtin_amdgcn_s_setprio(1);                                            \
    _Pragma("unroll") for (int im = 0; im < 4; im++)                          \
      _Pragma("unroll") for (int jn = 0; jn < 4; jn++)                        \
        acc[im][jn] = __builtin_amdgcn_mfma_f32_16x16x32_bf16(                \
            af[im], bq[jn], acc[im][jn], 0, 0, 0);                            \
    __builtin_amdgcn_s_setprio(0);                                            \
    __builtin_amdgcn_s_barrier();                                             \
  } while (0)

template<int RELU, int ADDRES>
__global__ __launch_bounds__(512, 1)
void gemm3r_bt(const __hip_bfloat16* __restrict__ A, int lda,
               const __hip_bfloat16* __restrict__ B,
               const float* __restrict__ bias,
               __hip_bfloat16* __restrict__ C, int ldc,
               const __hip_bfloat16* __restrict__ Rr, int ldr,
               int K)
{
  // 3 ring buffers x (A 8192 + B 16384) elems = 147456 B LDS
  __shared__ __align__(16) __hip_bfloat16 lds[3][24576];

  const int tid  = threadIdx.x;
  const int lane = tid & 63;
  const int wave = tid >> 6;
  const int quad = lane >> 4;
  const int l16  = lane & 15;
  const int wm   = wave >> 2;   // 0..1 (M)
  const int wn   = wave & 3;    // 0..3 (N)

  // supertile remap (gy%4==0): 4 m-tiles per group, n fastest.
  const int gx  = gridDim.x;
  const int lin = blockIdx.y * gx + blockIdx.x;
  const int gsz = 4 * gx;
  const int mt  = (lin / gsz) * 4 + (lin & 3);
  const int nt  = (lin % gsz) >> 2;
  const int m0 = mt * 128;
  const int n0 = nt * 256;

  const __hip_bfloat16* Ab = A + (size_t)m0 * lda;
  const __hip_bfloat16* Bb = B + (size_t)n0 * K;

  // staging source coords: chunk p = tid + 512*s; row = p>>3 (A: s<2 rows
  // 0..127; B: s<4 rows 0..255); source col8 pre-swizzled with row&7.
  int arow[4], acol[4];
#pragma unroll
  for (int s = 0; s < 4; s++) {
    const int p = tid + (s << 9);
    arow[s] = p >> 3;
    acol[s] = ((p & 7) ^ (arow[s] & 7)) << 3;
  }

  f32x4 acc[4][4] = {};
  const int NK = K >> 6;

  // ---- prologue: stage tiles 0 and 1 (12 loads/thread); drain tile 0 ----
  R3_SA(0, 0);  R3_SB0(0, 0);  R3_SB1(0, 0);
  R3_SA(1, 64); R3_SB0(1, 64); R3_SB1(1, 64);
  asm volatile("s_waitcnt vmcnt(6)" ::: "memory");
  __builtin_amdgcn_s_barrier();

  for (int t = 0; t < NK; ++t) {
    const int r  = t % 3;
    const int rn = (t + 2) % 3;
    const int k2 = (t + 2) << 6;
    const bool pf = (t + 2) < NK;

    R3_PH(r, 0,
          if (pf) { R3_SA(rn, k2); R3_SB0(rn, k2); }, );
    R3_PH(r, 1,
          if (pf) { R3_SB1(rn, k2); },
          if (pf) { asm volatile("s_waitcnt vmcnt(6)" ::: "memory"); }
          else    { asm volatile("s_waitcnt vmcnt(0)" ::: "memory"); });
  }

  // ---- epilogue: C/D layout col = lane&15, row = quad*4 + reg ----
#pragma unroll
  for (int jn = 0; jn < 4; jn++) {
    const int col = n0 + wn * 64 + jn * 16 + l16;
    const float bv = bias[col];
#pragma unroll
    for (int im = 0; im < 4; im++) {
      const int row0 = m0 + wm * 64 + im * 16 + quad * 4;
      const f32x4 a = acc[im][jn];
#pragma unroll
      for (int rr = 0; rr < 4; rr++) {
        float v = a[rr] + bv;
        if (RELU) v = fmaxf(v, 0.f);
        if (ADDRES) v += __bfloat162float(Rr[(size_t)(row0 + rr) * ldr + col]);
        C[(size_t)(row0 + rr) * ldc + col] = __float2bfloat16(v);
      }
    }
  }
}

// ---------------------------------------------------------------------------
// Banded attention (one wave per (s,b,h)).
// ---------------------------------------------------------------------------
__global__ __launch_bounds__(256)
void attn_k(__hip_bfloat16* __restrict__ qkv)
{
  const int gw   = (blockIdx.x << 2) + (threadIdx.x >> 6);
  const int lane = threadIdx.x & 63;
  const int h = gw & (NHEADS - 1);
  const int b = (gw >> 2) & (BATCH - 1);
  const int s = gw >> 4;
  const size_t hoff = (size_t)h * DHEAD + (lane << 2);

  float q0, q1, q2, q3;
  {
    uint2 t = *(const uint2*)(qkv + (size_t)(s * BATCH + b) * QKV_LD + hoff);
    q0 = bfbits2f(t.x & 0xffff); q1 = bfbits2f(t.x >> 16);
    q2 = bfbits2f(t.y & 0xffff); q3 = bfbits2f(t.y >> 16);
  }

  float sc[WIN + 1];
#pragma unroll
  for (int jj = 0; jj <= WIN; jj++) {
    int j = s - WIN + jj;           // wave-uniform
    float v = -1e30f;
    if (j >= 0) {
      uint2 t = *(const uint2*)(qkv + (size_t)(j * BATCH + b) * QKV_LD + H_DIM + hoff);
      float p = q0 * bfbits2f(t.x & 0xffff) + q1 * bfbits2f(t.x >> 16)
              + q2 * bfbits2f(t.y & 0xffff) + q3 * bfbits2f(t.y >> 16);
#pragma unroll
      for (int o = 32; o; o >>= 1) p += __shfl_xor(p, o);
      v = p * 0.0625f;              // 1/sqrt(256)
    }
    sc[jj] = v;
  }

  float mx = sc[0];
#pragma unroll
  for (int jj = 1; jj <= WIN; jj++) mx = fmaxf(mx, sc[jj]);
  float p[WIN + 1], den = 0.f;
#pragma unroll
  for (int jj = 0; jj <= WIN; jj++) { p[jj] = __expf(sc[jj] - mx); den += p[jj]; }

  float a0 = 0.f, a1 = 0.f, a2 = 0.f, a3 = 0.f;
#pragma unroll
  for (int jj = 0; jj <= WIN; jj++) {
    int j = s - WIN + jj;
    if (j >= 0) {
      uint2 t = *(const uint2*)(qkv + (size_t)(j * BATCH + b) * QKV_LD + 2 * H_DIM + hoff);
      a0 += p[jj] * bfbits2f(t.x & 0xffff); a1 += p[jj] * bfbits2f(t.x >> 16);
      a2 += p[jj] * bfbits2f(t.y & 0xffff); a3 += p[jj] * bfbits2f(t.y >> 16);
    }
  }
  float rl = 1.f / den;
  uint2 o;
  o.x = (unsigned)f2bfbits(a0 * rl) | ((unsigned)f2bfbits(a1 * rl) << 16);
  o.y = (unsigned)f2bfbits(a2 * rl) | ((unsigned)f2bfbits(a3 * rl) << 16);
  *(uint2*)(qkv + (size_t)(s * BATCH + b) * QKV_LD + hoff) = o;  // ctx -> q slot
}

// ---------------------------------------------------------------------------
// LayerNorm, one wave per row (shuffle-only).
// ---------------------------------------------------------------------------
__global__ __launch_bounds__(256)
void ln_k(const __hip_bfloat16* __restrict__ y, int ys,
          const float* __restrict__ g, const float* __restrict__ be,
          __hip_bfloat16* __restrict__ xout)
{
  const int row  = blockIdx.x * 4 + (threadIdx.x >> 6);
  const int lane = threadIdx.x & 63;
  const int e0   = lane * 16;
  const __hip_bfloat16* yp = y + (size_t)row * ys + e0;

  uint2 v[4];
  *(uint4*)&v[0] = *(const uint4*)yp;
  *(uint4*)&v[2] = *(const uint4*)(yp + 8);
  float t[16];
#pragma unroll
  for (int k = 0; k < 4; k++) {
    t[k * 4 + 0] = bfbits2f(v[k].x & 0xffff);
    t[k * 4 + 1] = bfbits2f(v[k].x >> 16);
    t[k * 4 + 2] = bfbits2f(v[k].y & 0xffff);
    t[k * 4 + 3] = bfbits2f(v[k].y >> 16);
  }
  float s = 0.f, ss = 0.f;
#pragma unroll
  for (int k = 0; k < 16; k++) { s += t[k]; ss += t[k] * t[k]; }
#pragma unroll
  for (int o = 32; o; o >>= 1) { s += __shfl_xor(s, o); ss += __shfl_xor(ss, o); }

  const float inv  = 1.f / (float)H_DIM;
  const float mean = s * inv;
  const float var  = ss * inv - mean * mean;   // biased var (jnp.var default)
  const float rstd = rsqrtf(var + 1e-5f);

  float4 gv[4], bv[4];
#pragma unroll
  for (int k = 0; k < 4; k++) {
    gv[k] = *(const float4*)(g + e0 + k * 4);
    bv[k] = *(const float4*)(be + e0 + k * 4);
  }
  uint2 ob[4];
#pragma unroll
  for (int k = 0; k < 4; k++) {
    float o0 = (t[k*4+0] - mean) * rstd * gv[k].x + bv[k].x;
    float o1 = (t[k*4+1] - mean) * rstd * gv[k].y + bv[k].y;
    float o2 = (t[k*4+2] - mean) * rstd * gv[k].z + bv[k].z;
    float o3 = (t[k*4+3] - mean) * rstd * gv[k].w + bv[k].w;
    ob[k].x = (unsigned)f2bfbits(o0) | ((unsigned)f2bfbits(o1) << 16);
    ob[k].y = (unsigned)f2bfbits(o2) | ((unsigned)f2bfbits(o3) << 16);
  }
  __hip_bfloat16* xp = xout + (size_t)row * H_DIM + e0;
  *(uint4*)xp       = *(const uint4*)&ob[0];
  *(uint4*)(xp + 8) = *(const uint4*)&ob[2];
}

// ---------------------------------------------------------------------------
extern "C" void kernel_launch(void* const* d_in, const int* in_sizes, int n_in,
                              void* d_out, int out_size, void* d_ws, size_t ws_size,
                              hipStream_t stream) {
  const float* src   = (const float*)d_in[0];
  const float* Wenc  = (const float*)d_in[1];
  const float* benc  = (const float*)d_in[2];
  const float* Wqkv  = (const float*)d_in[3];
  const float* bqkv  = (const float*)d_in[4];
  const float* Wo    = (const float*)d_in[5];
  const float* bo    = (const float*)d_in[6];
  const float* W1    = (const float*)d_in[7];
  const float* b1    = (const float*)d_in[8];
  const float* W2    = (const float*)d_in[9];
  const float* b2    = (const float*)d_in[10];
  const float* ln1s  = (const float*)d_in[11];
  const float* ln1b  = (const float*)d_in[12];
  const float* ln2s  = (const float*)d_in[13];
  const float* ln2b  = (const float*)d_in[14];
  const float* Wout  = (const float*)d_in[15];
  const float* bout  = (const float*)d_in[16];

  // ---- workspace (104 MiB total — footprint validated rounds 3/6) ----
  char* ws = (char*)d_ws;
  __hip_bfloat16* WB   = (__hip_bfloat16*)ws;      // bf16 arena (~37.3 MiB)
  __hip_bfloat16* srcb = WB;                       //   524288
  __hip_bfloat16* wenc = WB + 524288;              //    65536
  __hip_bfloat16* wqkv = WB + 589824;              //  9437184
  __hip_bfloat16* wo   = WB + 10027008;            //  3145728
  __hip_bfloat16* w1   = WB + 13172736;            //  3145728
  __hip_bfloat16* w2   = WB + 16318464;            //  3145728
  __hip_bfloat16* wout = WB + 19464192;            //    65536
  __hip_bfloat16* xb  = (__hip_bfloat16*)(ws + (size_t)40 * 1048576);  // 16 MiB
  __hip_bfloat16* qkv = (__hip_bfloat16*)(ws + (size_t)56 * 1048576);  // 48 MiB
  __hip_bfloat16* ctxp = qkv;             // q slot — attn output
  __hip_bfloat16* ybuf = qkv + H_DIM;     // k slot — (x + attn_out) / (x + ff)
  __hip_bfloat16* hbuf = qkv + 2 * H_DIM; // v slot — relu hidden temp

  const dim3 blk(256);
  const dim3 blk512(512);

  // ---- ingest: all fp32 weights/src -> bf16 in ONE dispatch ----
  {
    CvtSeg s0{src,  srcb, 524288 / 4};
    CvtSeg s1{Wenc, wenc, 65536 / 4};
    CvtSeg s2{Wqkv, wqkv, 9437184 / 4};
    CvtSeg s3{Wo,   wo,   3145728 / 4};
    CvtSeg s4{W1,   w1,   3145728 / 4};
    CvtSeg s5{W2,   w2,   3145728 / 4};
    CvtSeg s6{Wout, wout, 65536 / 4};
    const int tot4 = (524288 + 65536 + 9437184 + 3 * 3145728 + 65536) / 4;
    cvt_all_k<<<dim3((tot4 + 255) / 256), blk, 0, stream>>>(s0, s1, s2, s3, s4, s5, s6);
  }

  // ---- encoder: x = src @ Wenc^T + benc   [8192,1024] (K=64 -> 1 tile) ----
  gemm_bt<0, 0, 0><<<dim3(H_DIM / 128, ROWS / 128), blk, 0, stream>>>(
      srcb, IN_DIM, wenc, benc, xb, H_DIM, nullptr, 0, ROWS, H_DIM, IN_DIM);

  for (int l = 0; l < NLAYER; l++) {
    // qkv = x @ Wqkv^T + bqkv   [8192,3072] — 768 blocks = 3 exact rounds
    gemm3r_bt<0, 0><<<dim3(QKV_LD / 256, ROWS / 128), blk512, 0, stream>>>(
        xb, H_DIM, wqkv + (size_t)l * QKV_LD * H_DIM, bqkv + l * QKV_LD,
        qkv, QKV_LD, nullptr, 0, H_DIM);
    // banded attention; ctx -> q slot
    attn_k<<<dim3(ROWS * NHEADS / 4), blk, 0, stream>>>(qkv);
    // ybuf = x + ctx @ Wo^T + bo   (residual fused) — 256 blocks = 1 round
    gemm3r_bt<0, 1><<<dim3(H_DIM / 256, ROWS / 128), blk512, 0, stream>>>(
        ctxp, QKV_LD, wo + (size_t)l * H_DIM * H_DIM, bo + l * H_DIM,
        ybuf, QKV_LD, xb, H_DIM, H_DIM);
    // x = LN(ybuf)
    ln_k<<<dim3(ROWS / 4), blk, 0, stream>>>(ybuf, QKV_LD, ln1s + l * H_DIM, ln1b + l * H_DIM, xb);
    // h = relu(x @ W1^T + b1) -> hbuf (v slot)
    gemm3r_bt<1, 0><<<dim3(DFF_DIM / 256, ROWS / 128), blk512, 0, stream>>>(
        xb, H_DIM, w1 + (size_t)l * DFF_DIM * H_DIM, b1 + l * DFF_DIM,
        hbuf, QKV_LD, nullptr, 0, H_DIM);
    // ybuf = x + h @ W2^T + b2   (residual fused)
    gemm3r_bt<0, 1><<<dim3(H_DIM / 256, ROWS / 128), blk512, 0, stream>>>(
        hbuf, QKV_LD, w2 + (size_t)l * H_DIM * DFF_DIM, b2 + l * H_DIM,
        ybuf, QKV_LD, xb, H_DIM, DFF_DIM);
    // x = LN(ybuf)
    ln_k<<<dim3(ROWS / 4), blk, 0, stream>>>(ybuf, QKV_LD, ln2s + l * H_DIM, ln2b + l * H_DIM, xb);
  }

  // ---- decoder: out = x @ Wout^T + bout   [8192,64] FP32 OUTPUT ----
  gemm_bt<0, 1, 0><<<dim3(1, ROWS / 128), blk, 0, stream>>>(
      xb, H_DIM, wout, bout, d_out, OUT_DIM, nullptr, 0, ROWS, OUT_DIM, H_DIM);
}